// Round 4
// baseline (798.424 us; speedup 1.0000x reference)
//
#include <hip/hip_runtime.h>
#include <hip/hip_bf16.h>

#define TSZ 2048
#define NCH 8

__global__ __launch_bounds__(256) void hybrid_texmlp_kernel(
    const float* __restrict__ uv,
    const float* __restrict__ vd,
    const float* __restrict__ tex,   // [8,2048,2048]
    const float* __restrict__ w1, const float* __restrict__ b1,   // [16,11],[16]
    const float* __restrict__ w2, const float* __restrict__ b2,   // [16,16],[16]
    const float* __restrict__ w3, const float* __restrict__ b3,   // [3,16],[3]
    float* __restrict__ out,         // [B,3]
    int B)
{
    __shared__ float sw1[16 * 11];
    __shared__ float sb1[16];
    __shared__ float sw2[16 * 16];
    __shared__ float sb2[16];
    __shared__ float sw3[3 * 16];
    __shared__ float sb3[3];

    const int t = threadIdx.x;
    // cooperative weight staging (515 floats total)
    for (int i = t; i < 16 * 11; i += 256) sw1[i] = w1[i];
    for (int i = t; i < 16 * 16; i += 256) sw2[i] = w2[i];
    for (int i = t; i < 3 * 16;  i += 256) sw3[i] = w3[i];
    if (t < 16) { sb1[t] = b1[t]; sb2[t] = b2[t]; }
    if (t < 3)  { sb3[t] = b3[t]; }
    __syncthreads();

    const int idx = blockIdx.x * 256 + t;
    if (idx >= B) return;

    // ---- bilinear sample coords (align_corners=True, border clamp) ----
    const float2 uv2 = reinterpret_cast<const float2*>(uv)[idx];
    const float fx = fminf(fmaxf((uv2.x + 1.0f) * 0.5f * (float)(TSZ - 1), 0.0f), (float)(TSZ - 1));
    const float fy = fminf(fmaxf((uv2.y + 1.0f) * 0.5f * (float)(TSZ - 1), 0.0f), (float)(TSZ - 1));
    const float x0f = floorf(fx);
    const float y0f = floorf(fy);
    const float wx = fx - x0f;
    const float wy = fy - y0f;
    const int x0 = (int)x0f;
    const int y0 = (int)y0f;
    const int x1 = min(x0 + 1, TSZ - 1);
    const int y1 = min(y0 + 1, TSZ - 1);

    const float w00 = (1.0f - wx) * (1.0f - wy);
    const float w01 = wx * (1.0f - wy);
    const float w10 = (1.0f - wx) * wy;
    const float w11 = wx * wy;

    const size_t o00 = (size_t)y0 * TSZ + x0;
    const size_t o01 = (size_t)y0 * TSZ + x1;
    const size_t o10 = (size_t)y1 * TSZ + x0;
    const size_t o11 = (size_t)y1 * TSZ + x1;

    float xin[11];
#pragma unroll
    for (int c = 0; c < NCH; ++c) {
        const float* __restrict__ p = tex + (size_t)c * (TSZ * TSZ);
        const float f00 = p[o00];
        const float f01 = p[o01];
        const float f10 = p[o10];
        const float f11 = p[o11];
        xin[c] = f00 * w00 + f01 * w01 + f10 * w10 + f11 * w11;
    }
    xin[8]  = vd[3 * (size_t)idx + 0];
    xin[9]  = vd[3 * (size_t)idx + 1];
    xin[10] = vd[3 * (size_t)idx + 2];

    // ---- MLP: 11 -> 16 (relu) -> 16 (relu) -> 3 (sigmoid) ----
    float h1[16];
#pragma unroll
    for (int j = 0; j < 16; ++j) {
        float a = sb1[j];
#pragma unroll
        for (int i = 0; i < 11; ++i) a += xin[i] * sw1[j * 11 + i];
        h1[j] = fmaxf(a, 0.0f);
    }

    float h2[16];
#pragma unroll
    for (int j = 0; j < 16; ++j) {
        float a = sb2[j];
#pragma unroll
        for (int i = 0; i < 16; ++i) a += h1[i] * sw2[j * 16 + i];
        h2[j] = fmaxf(a, 0.0f);
    }

    float rgb[3];
#pragma unroll
    for (int k = 0; k < 3; ++k) {
        float a = sb3[k];
#pragma unroll
        for (int i = 0; i < 16; ++i) a += h2[i] * sw3[k * 16 + i];
        rgb[k] = 1.0f / (1.0f + __expf(-a));
    }

    out[3 * (size_t)idx + 0] = rgb[0];
    out[3 * (size_t)idx + 1] = rgb[1];
    out[3 * (size_t)idx + 2] = rgb[2];
}

extern "C" void kernel_launch(void* const* d_in, const int* in_sizes, int n_in,
                              void* d_out, int out_size, void* d_ws, size_t ws_size,
                              hipStream_t stream) {
    const float* uv  = (const float*)d_in[0];
    const float* vd  = (const float*)d_in[1];
    const float* tex = (const float*)d_in[2];
    const float* w1  = (const float*)d_in[3];
    const float* b1  = (const float*)d_in[4];
    const float* w2  = (const float*)d_in[5];
    const float* b2  = (const float*)d_in[6];
    const float* w3  = (const float*)d_in[7];
    const float* b3  = (const float*)d_in[8];
    float* out = (float*)d_out;

    const int B = in_sizes[0] / 2;
    const int block = 256;
    const int grid = (B + block - 1) / block;
    hybrid_texmlp_kernel<<<grid, block, 0, stream>>>(
        uv, vd, tex, w1, b1, w2, b2, w3, b3, out, B);
}

// Round 8
// 325.495 us; speedup vs baseline: 2.4530x; 2.4530x over previous
//
#include <hip/hip_runtime.h>
#include <hip/hip_bf16.h>

#define TSZ 2048
#define NCH 8
#define NPIX (TSZ * TSZ)

__device__ __forceinline__ unsigned pack_bf16_rne(float a, float b) {
    unsigned ua = __float_as_uint(a);
    unsigned ub = __float_as_uint(b);
    ua += 0x7fffu + ((ua >> 16) & 1u);   // round-to-nearest-even
    ub += 0x7fffu + ((ub >> 16) & 1u);
    return (ua >> 16) | (ub & 0xffff0000u);
}
__device__ __forceinline__ float blo(unsigned u) { return __uint_as_float(u << 16); }
__device__ __forceinline__ float bhi(unsigned u) { return __uint_as_float(u & 0xffff0000u); }

// ---------------------------------------------------------------------------
// Pass 1: transpose+pack texture [C,H,W] fp32 -> [H,W,C] bf16 (16B/texel).
// Reads: 8 coalesced plane streams. Writes: one dwordx4 per thread, dense.
// ---------------------------------------------------------------------------
__global__ __launch_bounds__(256) void transpose_pack_kernel(
    const float* __restrict__ tex, uint4* __restrict__ txp)
{
    const int p = blockIdx.x * 256 + threadIdx.x;   // texel index y*TSZ+x
    float v[NCH];
#pragma unroll
    for (int c = 0; c < NCH; ++c)
        v[c] = tex[(size_t)c * NPIX + p];
    uint4 q;
    q.x = pack_bf16_rne(v[0], v[1]);
    q.y = pack_bf16_rne(v[2], v[3]);
    q.z = pack_bf16_rne(v[4], v[5]);
    q.w = pack_bf16_rne(v[6], v[7]);
    txp[p] = q;
}

// ---------------------------------------------------------------------------
// Pass 2: gather from bf16 [H,W,C] (one dwordx4 per corner) + fp32 MLP.
// ---------------------------------------------------------------------------
__global__ __launch_bounds__(256) void gather_mlp_kernel(
    const float* __restrict__ uv,
    const float* __restrict__ vd,
    const uint4* __restrict__ txp,   // [2048*2048] packed bf16 x8
    const float* __restrict__ w1, const float* __restrict__ b1,
    const float* __restrict__ w2, const float* __restrict__ b2,
    const float* __restrict__ w3, const float* __restrict__ b3,
    float* __restrict__ out, int B)
{
    __shared__ float sw1[16 * 11];
    __shared__ float sb1[16];
    __shared__ float sw2[16 * 16];
    __shared__ float sb2[16];
    __shared__ float sw3[3 * 16];
    __shared__ float sb3[3];

    const int t = threadIdx.x;
    for (int i = t; i < 16 * 11; i += 256) sw1[i] = w1[i];
    for (int i = t; i < 16 * 16; i += 256) sw2[i] = w2[i];
    for (int i = t; i < 3 * 16;  i += 256) sw3[i] = w3[i];
    if (t < 16) { sb1[t] = b1[t]; sb2[t] = b2[t]; }
    if (t < 3)  { sb3[t] = b3[t]; }
    __syncthreads();

    const int idx = blockIdx.x * 256 + t;
    if (idx >= B) return;

    const float2 uv2 = reinterpret_cast<const float2*>(uv)[idx];
    const float fx = fminf(fmaxf((uv2.x + 1.0f) * 0.5f * (float)(TSZ - 1), 0.0f), (float)(TSZ - 1));
    const float fy = fminf(fmaxf((uv2.y + 1.0f) * 0.5f * (float)(TSZ - 1), 0.0f), (float)(TSZ - 1));
    const float x0f = floorf(fx);
    const float y0f = floorf(fy);
    const float wx = fx - x0f;
    const float wy = fy - y0f;
    const int x0 = (int)x0f;
    const int y0 = (int)y0f;
    const int x1 = min(x0 + 1, TSZ - 1);
    const int y1 = min(y0 + 1, TSZ - 1);

    const float w00 = (1.0f - wx) * (1.0f - wy);
    const float w01 = wx * (1.0f - wy);
    const float w10 = (1.0f - wx) * wy;
    const float w11 = wx * wy;

    const uint4 q00 = txp[(size_t)y0 * TSZ + x0];
    const uint4 q01 = txp[(size_t)y0 * TSZ + x1];
    const uint4 q10 = txp[(size_t)y1 * TSZ + x0];
    const uint4 q11 = txp[(size_t)y1 * TSZ + x1];

    float xin[11];
    xin[0] = blo(q00.x) * w00 + blo(q01.x) * w01 + blo(q10.x) * w10 + blo(q11.x) * w11;
    xin[1] = bhi(q00.x) * w00 + bhi(q01.x) * w01 + bhi(q10.x) * w10 + bhi(q11.x) * w11;
    xin[2] = blo(q00.y) * w00 + blo(q01.y) * w01 + blo(q10.y) * w10 + blo(q11.y) * w11;
    xin[3] = bhi(q00.y) * w00 + bhi(q01.y) * w01 + bhi(q10.y) * w10 + bhi(q11.y) * w11;
    xin[4] = blo(q00.z) * w00 + blo(q01.z) * w01 + blo(q10.z) * w10 + blo(q11.z) * w11;
    xin[5] = bhi(q00.z) * w00 + bhi(q01.z) * w01 + bhi(q10.z) * w10 + bhi(q11.z) * w11;
    xin[6] = blo(q00.w) * w00 + blo(q01.w) * w01 + blo(q10.w) * w10 + blo(q11.w) * w11;
    xin[7] = bhi(q00.w) * w00 + bhi(q01.w) * w01 + bhi(q10.w) * w10 + bhi(q11.w) * w11;
    xin[8]  = vd[3 * (size_t)idx + 0];
    xin[9]  = vd[3 * (size_t)idx + 1];
    xin[10] = vd[3 * (size_t)idx + 2];

    float h1[16];
#pragma unroll
    for (int j = 0; j < 16; ++j) {
        float a = sb1[j];
#pragma unroll
        for (int i = 0; i < 11; ++i) a += xin[i] * sw1[j * 11 + i];
        h1[j] = fmaxf(a, 0.0f);
    }

    float h2[16];
#pragma unroll
    for (int j = 0; j < 16; ++j) {
        float a = sb2[j];
#pragma unroll
        for (int i = 0; i < 16; ++i) a += h1[i] * sw2[j * 16 + i];
        h2[j] = fmaxf(a, 0.0f);
    }

    float rgb[3];
#pragma unroll
    for (int k = 0; k < 3; ++k) {
        float a = sb3[k];
#pragma unroll
        for (int i = 0; i < 16; ++i) a += h2[i] * sw3[k * 16 + i];
        rgb[k] = 1.0f / (1.0f + __expf(-a));
    }

    out[3 * (size_t)idx + 0] = rgb[0];
    out[3 * (size_t)idx + 1] = rgb[1];
    out[3 * (size_t)idx + 2] = rgb[2];
}

// ---------------------------------------------------------------------------
// Fallback: baseline one-pass kernel (channel-major gather) if ws too small.
// ---------------------------------------------------------------------------
__global__ __launch_bounds__(256) void hybrid_texmlp_kernel(
    const float* __restrict__ uv,
    const float* __restrict__ vd,
    const float* __restrict__ tex,
    const float* __restrict__ w1, const float* __restrict__ b1,
    const float* __restrict__ w2, const float* __restrict__ b2,
    const float* __restrict__ w3, const float* __restrict__ b3,
    float* __restrict__ out, int B)
{
    __shared__ float sw1[16 * 11];
    __shared__ float sb1[16];
    __shared__ float sw2[16 * 16];
    __shared__ float sb2[16];
    __shared__ float sw3[3 * 16];
    __shared__ float sb3[3];

    const int t = threadIdx.x;
    for (int i = t; i < 16 * 11; i += 256) sw1[i] = w1[i];
    for (int i = t; i < 16 * 16; i += 256) sw2[i] = w2[i];
    for (int i = t; i < 3 * 16;  i += 256) sw3[i] = w3[i];
    if (t < 16) { sb1[t] = b1[t]; sb2[t] = b2[t]; }
    if (t < 3)  { sb3[t] = b3[t]; }
    __syncthreads();

    const int idx = blockIdx.x * 256 + t;
    if (idx >= B) return;

    const float2 uv2 = reinterpret_cast<const float2*>(uv)[idx];
    const float fx = fminf(fmaxf((uv2.x + 1.0f) * 0.5f * (float)(TSZ - 1), 0.0f), (float)(TSZ - 1));
    const float fy = fminf(fmaxf((uv2.y + 1.0f) * 0.5f * (float)(TSZ - 1), 0.0f), (float)(TSZ - 1));
    const float x0f = floorf(fx);
    const float y0f = floorf(fy);
    const float wx = fx - x0f;
    const float wy = fy - y0f;
    const int x0 = (int)x0f;
    const int y0 = (int)y0f;
    const int x1 = min(x0 + 1, TSZ - 1);
    const int y1 = min(y0 + 1, TSZ - 1);

    const float w00 = (1.0f - wx) * (1.0f - wy);
    const float w01 = wx * (1.0f - wy);
    const float w10 = (1.0f - wx) * wy;
    const float w11 = wx * wy;

    const size_t o00 = (size_t)y0 * TSZ + x0;
    const size_t o01 = (size_t)y0 * TSZ + x1;
    const size_t o10 = (size_t)y1 * TSZ + x0;
    const size_t o11 = (size_t)y1 * TSZ + x1;

    float xin[11];
#pragma unroll
    for (int c = 0; c < NCH; ++c) {
        const float* __restrict__ p = tex + (size_t)c * NPIX;
        xin[c] = p[o00] * w00 + p[o01] * w01 + p[o10] * w10 + p[o11] * w11;
    }
    xin[8]  = vd[3 * (size_t)idx + 0];
    xin[9]  = vd[3 * (size_t)idx + 1];
    xin[10] = vd[3 * (size_t)idx + 2];

    float h1[16];
#pragma unroll
    for (int j = 0; j < 16; ++j) {
        float a = sb1[j];
#pragma unroll
        for (int i = 0; i < 11; ++i) a += xin[i] * sw1[j * 11 + i];
        h1[j] = fmaxf(a, 0.0f);
    }
    float h2[16];
#pragma unroll
    for (int j = 0; j < 16; ++j) {
        float a = sb2[j];
#pragma unroll
        for (int i = 0; i < 16; ++i) a += h1[i] * sw2[j * 16 + i];
        h2[j] = fmaxf(a, 0.0f);
    }
    float rgb[3];
#pragma unroll
    for (int k = 0; k < 3; ++k) {
        float a = sb3[k];
#pragma unroll
        for (int i = 0; i < 16; ++i) a += h2[i] * sw3[k * 16 + i];
        rgb[k] = 1.0f / (1.0f + __expf(-a));
    }

    out[3 * (size_t)idx + 0] = rgb[0];
    out[3 * (size_t)idx + 1] = rgb[1];
    out[3 * (size_t)idx + 2] = rgb[2];
}

extern "C" void kernel_launch(void* const* d_in, const int* in_sizes, int n_in,
                              void* d_out, int out_size, void* d_ws, size_t ws_size,
                              hipStream_t stream) {
    const float* uv  = (const float*)d_in[0];
    const float* vd  = (const float*)d_in[1];
    const float* tex = (const float*)d_in[2];
    const float* w1  = (const float*)d_in[3];
    const float* b1  = (const float*)d_in[4];
    const float* w2  = (const float*)d_in[5];
    const float* b2  = (const float*)d_in[6];
    const float* w3  = (const float*)d_in[7];
    const float* b3  = (const float*)d_in[8];
    float* out = (float*)d_out;

    const int B = in_sizes[0] / 2;
    const int block = 256;
    const int grid = (B + block - 1) / block;

    const size_t need = (size_t)NPIX * 16;  // 64 MiB packed bf16 [H,W,C]
    if (ws_size >= need) {
        uint4* txp = (uint4*)d_ws;
        transpose_pack_kernel<<<NPIX / block, block, 0, stream>>>(tex, txp);
        gather_mlp_kernel<<<grid, block, 0, stream>>>(
            uv, vd, txp, w1, b1, w2, b2, w3, b3, out, B);
    } else {
        hybrid_texmlp_kernel<<<grid, block, 0, stream>>>(
            uv, vd, tex, w1, b1, w2, b2, w3, b3, out, B);
    }
}